// Round 2
// baseline (83.329 us; speedup 1.0000x reference)
//
#include <hip/hip_runtime.h>
#include <hip/hip_bf16.h>

#define BDIM 256
#define NDIM 512
#define CDIM 1000
#define RDIM 64
#define BK 64
#define NT (NDIM / BK)   // 8 K-tiles

typedef __attribute__((ext_vector_type(4))) float f32x4;
typedef __attribute__((ext_vector_type(8))) short bf16x8;

__device__ __forceinline__ uint32_t pk2(float lo, float hi) {
    unsigned short l = __builtin_bit_cast(unsigned short, __float2bfloat16(lo));
    unsigned short h = __builtin_bit_cast(unsigned short, __float2bfloat16(hi));
    return ((uint32_t)h << 16) | (uint32_t)l;
}

__device__ __forceinline__ void gload16(const void* g, void* l) {
    __builtin_amdgcn_global_load_lds(
        (const __attribute__((address_space(1))) void*)g,
        (__attribute__((address_space(3))) void*)l, 16, 0, 0);
}

// ---------------------------------------------------------------------------
// Pre-pass: x fp32 [256][512] -> bf16 tile images in d_ws.
// 8 tiles of 32 KB; tile t, byte offset P = row*128 + sIn where
// sIn = uIn ^ ((row&7)<<4), uIn/2 = element index within the 64-col tile.
// This is exactly the swizzled LDS image, so the main kernel's linear
// global_load_lds reproduces it verbatim.
// ---------------------------------------------------------------------------
__global__ __launch_bounds__(256)
void Mahalanobis_xconv_kernel(const float* __restrict__ x, uint4* __restrict__ xws)
{
    const int tid = blockIdx.x * 256 + threadIdx.x;   // 0..16383
    const int t   = tid >> 11;                        // tile 0..7
    const int rem = tid & 2047;
    const int row = rem >> 3;                         // 0..255
    const int sIn = (rem & 7) << 4;                   // swizzled inner byte
    const int uIn = sIn ^ ((row & 7) << 4);           // unswizzled inner byte
    const int col0 = t * BK + (uIn >> 1);             // element column in x
    const float4* src = reinterpret_cast<const float4*>(x + (size_t)row * NDIM + col0);
    const float4 a = src[0], b = src[1];
    uint4 pk = {pk2(a.x, a.y), pk2(a.z, a.w), pk2(b.x, b.y), pk2(b.z, b.w)};
    xws[tid] = pk;                                    // byte offset = tid*16
}

// ---------------------------------------------------------------------------
// Main kernel: pipelined (issue-early W, async x via global_load_lds)
// ---------------------------------------------------------------------------
__global__ __launch_bounds__(256, 2)
void Mahalanobis_72834055405642_kernel(const char* __restrict__ xws,
                                       const float* __restrict__ w,
                                       const float* __restrict__ bias,
                                       float* __restrict__ out)
{
    __shared__ alignas(16) char lds_x[BDIM * BK * 2];     // 32 KB, single-buffered
    __shared__ alignas(16) char lds_w[2][128 * BK * 2];   // 2 x 16 KB, double-buffered
    __shared__ alignas(16) float bias_lds[2 * NDIM];      // 4 KB
    __shared__ float sb_lds[128];

    const int tid  = threadIdx.x;
    const int lane = tid & 63;
    const int wv   = tid >> 6;
    const int l15  = lane & 15;
    const int lhi  = lane >> 4;
    const int c0   = blockIdx.x * 2;

    // stage bias rows c0, c0+1
    reinterpret_cast<float4*>(bias_lds)[tid] =
        reinterpret_cast<const float4*>(bias + (size_t)c0 * NDIM)[tid];

    // W addressing: 128 tile rows x 64 cols, 2 threads per row (32-col halves)
    const int jrow = tid >> 1;
    const int jh   = tid & 1;
    const int cl   = jrow >> 6;
    const float* wbase  = w + (size_t)(c0 + cl) * (RDIM * NDIM)
                            + (size_t)(jrow & 63) * NDIM + jh * 32;
    const float* blbase = bias_lds + cl * NDIM + jh * 32;

    f32x4 acc[4][8];
    #pragma unroll
    for (int m = 0; m < 4; ++m)
        #pragma unroll
        for (int n = 0; n < 8; ++n)
            acc[m][n] = (f32x4){0.f, 0.f, 0.f, 0.f};

    float sbp = 0.f;
    const int swr = (l15 & 7) << 4;

    // ---- prologue: tile 0 ----
    {
        f32x4 wr[8];
        const f32x4* src = reinterpret_cast<const f32x4*>(wbase);
        #pragma unroll
        for (int i = 0; i < 8; ++i) wr[i] = __builtin_nontemporal_load(src + i);
        #pragma unroll
        for (int q = 0; q < 8; ++q)
            gload16(xws + wv * 8192 + q * 1024 + lane * 16,
                    lds_x + wv * 8192 + q * 1024);
        __syncthreads();   // bias visible (x gloads also drained; prologue, cheap)
        const f32x4* bl = reinterpret_cast<const f32x4*>(blbase);
        char* rowp = lds_w[0] + jrow * 128;
        const int sw = (jrow & 7) << 4;
        #pragma unroll
        for (int i2 = 0; i2 < 4; ++i2) {
            f32x4 va = wr[i2 * 2], vb = wr[i2 * 2 + 1];
            f32x4 ba = bl[i2 * 2], bb = bl[i2 * 2 + 1];
            sbp += va[0]*ba[0] + va[1]*ba[1] + va[2]*ba[2] + va[3]*ba[3]
                 + vb[0]*bb[0] + vb[1]*bb[1] + vb[2]*bb[2] + vb[3]*bb[3];
            uint4 pkv = {pk2(va[0], va[1]), pk2(va[2], va[3]),
                         pk2(vb[0], vb[1]), pk2(vb[2], vb[3])};
            *reinterpret_cast<uint4*>(rowp + ((jh * 64 + i2 * 16) ^ sw)) = pkv;
        }
        __syncthreads();
    }

    // ---- main loop ----
    #pragma unroll
    for (int t = 0; t < NT; ++t) {
        const int cur = t & 1;

        // issue next W tile early (HBM latency hides under frags + MFMA)
        f32x4 wr[8];
        if (t < NT - 1) {
            const f32x4* src = reinterpret_cast<const f32x4*>(wbase + (t + 1) * BK);
            #pragma unroll
            for (int i = 0; i < 8; ++i) wr[i] = __builtin_nontemporal_load(src + i);
        }

        // A-frags from single-buffered x LDS (must finish before barrier #1)
        bf16x8 af[4][2];
        #pragma unroll
        for (int m = 0; m < 4; ++m) {
            const int row = wv * 64 + m * 16 + l15;
            #pragma unroll
            for (int ks = 0; ks < 2; ++ks)
                af[m][ks] = *reinterpret_cast<const bf16x8*>(
                    lds_x + row * 128 + ((ks * 64 + lhi * 16) ^ swr));
        }

        // barrier #1: LDS reads drained, but W loads stay in flight (no vmcnt!)
        asm volatile("s_waitcnt lgkmcnt(0)" ::: "memory");
        __builtin_amdgcn_sched_barrier(0);
        __builtin_amdgcn_s_barrier();
        __builtin_amdgcn_sched_barrier(0);

        // async-stage next x tile into the (now free) x buffer
        if (t < NT - 1) {
            #pragma unroll
            for (int q = 0; q < 8; ++q)
                gload16(xws + (t + 1) * 32768 + wv * 8192 + q * 1024 + lane * 16,
                        lds_x + wv * 8192 + q * 1024);
        }

        // MFMA phase
        #pragma unroll
        for (int ks = 0; ks < 2; ++ks) {
            bf16x8 bfr[8];
            #pragma unroll
            for (int n = 0; n < 8; ++n) {
                const int row = n * 16 + l15;
                bfr[n] = *reinterpret_cast<const bf16x8*>(
                    lds_w[cur] + row * 128 + ((ks * 64 + lhi * 16) ^ swr));
            }
            __builtin_amdgcn_s_setprio(1);
            #pragma unroll
            for (int m = 0; m < 4; ++m)
                #pragma unroll
                for (int n = 0; n < 8; ++n)
                    acc[m][n] = __builtin_amdgcn_mfma_f32_16x16x32_bf16(
                        af[m][ks], bfr[n], acc[m][n], 0, 0, 0);
            __builtin_amdgcn_s_setprio(0);
        }

        // convert prefetched W (compiler inserts counted vmcnt), fused Sb, write other buffer
        if (t < NT - 1) {
            const f32x4* bl = reinterpret_cast<const f32x4*>(blbase + (t + 1) * BK);
            char* rowp = lds_w[cur ^ 1] + jrow * 128;
            const int sw = (jrow & 7) << 4;
            #pragma unroll
            for (int i2 = 0; i2 < 4; ++i2) {
                f32x4 va = wr[i2 * 2], vb = wr[i2 * 2 + 1];
                f32x4 ba = bl[i2 * 2], bb = bl[i2 * 2 + 1];
                sbp += va[0]*ba[0] + va[1]*ba[1] + va[2]*ba[2] + va[3]*ba[3]
                     + vb[0]*bb[0] + vb[1]*bb[1] + vb[2]*bb[2] + vb[3]*bb[3];
                uint4 pkv = {pk2(va[0], va[1]), pk2(va[2], va[3]),
                             pk2(vb[0], vb[1]), pk2(vb[2], vb[3])};
                *reinterpret_cast<uint4*>(rowp + ((jh * 64 + i2 * 16) ^ sw)) = pkv;
            }
        }

        __syncthreads();   // barrier #2: drains x gloads + W ds_writes
    }

    // ---- Sb: reduce col-half pairs, publish ----
    sbp += __shfl_xor(sbp, 1);
    if (jh == 0) sb_lds[jrow] = sbp;
    __syncthreads();

    float sb[8];
    #pragma unroll
    for (int n = 0; n < 8; ++n) sb[n] = sb_lds[n * 16 + l15];

    // ---- epilogue ----
    #pragma unroll
    for (int m = 0; m < 4; ++m) {
        #pragma unroll
        for (int rg = 0; rg < 4; ++rg) {
            float p0 = 0.f, p1 = 0.f;
            #pragma unroll
            for (int n = 0; n < 4; ++n) {
                const float d0 = acc[m][n][rg]     - sb[n];
                const float d1 = acc[m][n + 4][rg] - sb[n + 4];
                p0 += d0 * d0;
                p1 += d1 * d1;
            }
            #pragma unroll
            for (int s = 1; s < 16; s <<= 1) {
                p0 += __shfl_xor(p0, s);
                p1 += __shfl_xor(p1, s);
            }
            if (l15 == 0) {
                const int b = wv * 64 + m * 16 + lhi * 4 + rg;
                float2 o2 = {p0, p1};
                *reinterpret_cast<float2*>(out + (size_t)b * CDIM + c0) = o2;
            }
        }
    }
}

// ---------------------------------------------------------------------------
// Fallback (round-0 proven kernel) for the case ws_size < 256 KB
// ---------------------------------------------------------------------------
__global__ __launch_bounds__(256, 2)
void Mahalanobis_fallback_kernel(const float* __restrict__ x,
                                 const float* __restrict__ w,
                                 const float* __restrict__ bias,
                                 float* __restrict__ out)
{
    __shared__ alignas(16) char lds_x[BDIM * BK * 2];
    __shared__ alignas(16) char lds_w[128 * BK * 2];
    __shared__ alignas(16) float bias_lds[2 * NDIM];
    __shared__ float sb_lds[128];

    const int tid  = threadIdx.x;
    const int lane = tid & 63;
    const int wv   = tid >> 6;
    const int l15  = lane & 15;
    const int lhi  = lane >> 4;
    const int c0   = blockIdx.x * 2;

    reinterpret_cast<float4*>(bias_lds)[tid] =
        reinterpret_cast<const float4*>(bias + (size_t)c0 * NDIM)[tid];

    f32x4 acc[4][8];
    #pragma unroll
    for (int m = 0; m < 4; ++m)
        #pragma unroll
        for (int n = 0; n < 8; ++n)
            acc[m][n] = (f32x4){0.f, 0.f, 0.f, 0.f};

    const int jrow = tid >> 1;
    const int jh   = tid & 1;
    const int cl   = jrow >> 6;
    const float* wbase  = w + (size_t)(c0 + cl) * (RDIM * NDIM)
                            + (size_t)(jrow & 63) * NDIM + jh * 32;
    const float* blbase = bias_lds + cl * NDIM + jh * 32;
    const int xrow = tid >> 2;
    const int xq   = tid & 3;

    float sbp = 0.f;
    __syncthreads();

    for (int kk = 0; kk < NDIM; kk += BK) {
        #pragma unroll
        for (int p = 0; p < 4; ++p) {
            const int r = p * 64 + xrow;
            const float4* src = reinterpret_cast<const float4*>(
                x + (size_t)r * NDIM + kk + xq * 16);
            float4 v0 = src[0], v1 = src[1], v2 = src[2], v3 = src[3];
            uint4 pa = {pk2(v0.x, v0.y), pk2(v0.z, v0.w), pk2(v1.x, v1.y), pk2(v1.z, v1.w)};
            uint4 pb = {pk2(v2.x, v2.y), pk2(v2.z, v2.w), pk2(v3.x, v3.y), pk2(v3.z, v3.w)};
            const int sw = (r & 7) << 4;
            char* rowp = lds_x + r * (BK * 2);
            *reinterpret_cast<uint4*>(rowp + ((xq * 32) ^ sw))      = pa;
            *reinterpret_cast<uint4*>(rowp + ((xq * 32 + 16) ^ sw)) = pb;
        }
        {
            const float4* src = reinterpret_cast<const float4*>(wbase + kk);
            const float4* bl  = reinterpret_cast<const float4*>(blbase + kk);
            char* rowp = lds_w + jrow * (BK * 2);
            const int sw = (jrow & 7) << 4;
            #pragma unroll
            for (int i2 = 0; i2 < 4; ++i2) {
                float4 va = src[i2 * 2];
                float4 vb = src[i2 * 2 + 1];
                float4 ba = bl[i2 * 2];
                float4 bb = bl[i2 * 2 + 1];
                sbp += va.x * ba.x + va.y * ba.y + va.z * ba.z + va.w * ba.w
                     + vb.x * bb.x + vb.y * bb.y + vb.z * bb.z + vb.w * bb.w;
                uint4 pkv = {pk2(va.x, va.y), pk2(va.z, va.w),
                             pk2(vb.x, vb.y), pk2(vb.z, vb.w)};
                *reinterpret_cast<uint4*>(rowp + ((jh * 64 + i2 * 16) ^ sw)) = pkv;
            }
        }
        __syncthreads();
        #pragma unroll
        for (int ks = 0; ks < 2; ++ks) {
            bf16x8 af[4];
            bf16x8 bfr[8];
            const int swr = (l15 & 7) << 4;
            #pragma unroll
            for (int m = 0; m < 4; ++m) {
                const int row = wv * 64 + m * 16 + l15;
                af[m] = *reinterpret_cast<const bf16x8*>(
                    lds_x + row * (BK * 2) + ((ks * 64 + lhi * 16) ^ swr));
            }
            #pragma unroll
            for (int n = 0; n < 8; ++n) {
                const int row = n * 16 + l15;
                bfr[n] = *reinterpret_cast<const bf16x8*>(
                    lds_w + row * (BK * 2) + ((ks * 64 + lhi * 16) ^ swr));
            }
            #pragma unroll
            for (int m = 0; m < 4; ++m)
                #pragma unroll
                for (int n = 0; n < 8; ++n)
                    acc[m][n] = __builtin_amdgcn_mfma_f32_16x16x32_bf16(
                        af[m], bfr[n], acc[m][n], 0, 0, 0);
        }
        __syncthreads();
    }

    sbp += __shfl_xor(sbp, 1);
    if (jh == 0) sb_lds[jrow] = sbp;
    __syncthreads();

    float sb[8];
    #pragma unroll
    for (int n = 0; n < 8; ++n) sb[n] = sb_lds[n * 16 + l15];

    #pragma unroll
    for (int m = 0; m < 4; ++m) {
        #pragma unroll
        for (int rg = 0; rg < 4; ++rg) {
            float p0 = 0.f, p1 = 0.f;
            #pragma unroll
            for (int n = 0; n < 4; ++n) {
                const float d0 = acc[m][n][rg]     - sb[n];
                const float d1 = acc[m][n + 4][rg] - sb[n + 4];
                p0 += d0 * d0;
                p1 += d1 * d1;
            }
            #pragma unroll
            for (int s = 1; s < 16; s <<= 1) {
                p0 += __shfl_xor(p0, s);
                p1 += __shfl_xor(p1, s);
            }
            if (l15 == 0) {
                const int b = wv * 64 + m * 16 + lhi * 4 + rg;
                float2 o2 = {p0, p1};
                *reinterpret_cast<float2*>(out + (size_t)b * CDIM + c0) = o2;
            }
        }
    }
}

extern "C" void kernel_launch(void* const* d_in, const int* in_sizes, int n_in,
                              void* d_out, int out_size, void* d_ws, size_t ws_size,
                              hipStream_t stream) {
    const float* x    = (const float*)d_in[0];
    const float* w    = (const float*)d_in[1];
    const float* bias = (const float*)d_in[2];
    float* out = (float*)d_out;

    if (ws_size >= (size_t)(BDIM * NDIM * 2)) {   // 256 KB for bf16 x images
        hipLaunchKernelGGL(Mahalanobis_xconv_kernel, dim3(64), dim3(256), 0, stream,
                           x, (uint4*)d_ws);
        hipLaunchKernelGGL(Mahalanobis_72834055405642_kernel, dim3(CDIM / 2), dim3(256),
                           0, stream, (const char*)d_ws, w, bias, out);
    } else {
        hipLaunchKernelGGL(Mahalanobis_fallback_kernel, dim3(CDIM / 2), dim3(256),
                           0, stream, x, w, bias, out);
    }
}

// Round 3
// 50.815 us; speedup vs baseline: 1.6399x; 1.6399x over previous
//
#include <hip/hip_runtime.h>
#include <hip/hip_bf16.h>

#define BDIM 256
#define NDIM 512
#define CDIM 1000
#define RDIM 64
#define BK 64
#define NT (NDIM / BK)   // 8 K-tiles

typedef __attribute__((ext_vector_type(4))) float f32x4;
typedef __attribute__((ext_vector_type(8))) short bf16x8;

__device__ __forceinline__ uint32_t pk2(float lo, float hi) {
    unsigned short l = __builtin_bit_cast(unsigned short, __float2bfloat16(lo));
    unsigned short h = __builtin_bit_cast(unsigned short, __float2bfloat16(hi));
    return ((uint32_t)h << 16) | (uint32_t)l;
}

__device__ __forceinline__ void gload16(const void* g, void* l) {
    __builtin_amdgcn_global_load_lds(
        (const __attribute__((address_space(1))) void*)g,
        (__attribute__((address_space(3))) void*)l, 16, 0, 0);
}

// ---------------------------------------------------------------------------
// Pre-pass (PROVEN in round 2): x fp32 [256][512] -> bf16 swizzled tile
// images in d_ws. 8 tiles of 32 KB; within tile t, byte P = row*128 + sIn,
// sIn = uIn ^ ((row&7)<<4). Linear global_load_lds reproduces the swizzled
// LDS image verbatim (rule #21: pre-swizzled source + linear dest).
// ---------------------------------------------------------------------------
__global__ __launch_bounds__(256)
void Mahalanobis_xconv_kernel(const float* __restrict__ x, uint4* __restrict__ xws)
{
    const int tid = blockIdx.x * 256 + threadIdx.x;   // 0..16383
    const int t   = tid >> 11;                        // tile 0..7
    const int rem = tid & 2047;
    const int row = rem >> 3;                         // 0..255
    const int sIn = (rem & 7) << 4;                   // swizzled inner byte
    const int uIn = sIn ^ ((row & 7) << 4);           // unswizzled inner byte
    const int col0 = t * BK + (uIn >> 1);             // element column in x
    const float4* src = reinterpret_cast<const float4*>(x + (size_t)row * NDIM + col0);
    const float4 a = src[0], b = src[1];
    uint4 pk = {pk2(a.x, a.y), pk2(a.z, a.w), pk2(b.x, b.y), pk2(b.z, b.w)};
    xws[tid] = pk;
}

// ---------------------------------------------------------------------------
// Main kernel: round-1 proven serial structure, 1 class/block.
// Tile 256(b) x 64(r), grid = 1000 blocks, 4 waves, 3 blocks/CU target.
// ---------------------------------------------------------------------------
__global__ __launch_bounds__(256, 4)
void Mahalanobis_72834055405642_kernel(const char* __restrict__ xws,
                                       const float* __restrict__ w,
                                       const float* __restrict__ bias,
                                       float* __restrict__ out)
{
    __shared__ alignas(16) char lds_x[BDIM * BK * 2];   // 32 KB
    __shared__ alignas(16) char lds_w[RDIM * BK * 2];   // 8 KB
    __shared__ float sb_lds[RDIM];                      // 256 B

    const int tid  = threadIdx.x;
    const int lane = tid & 63;
    const int wv   = tid >> 6;
    const int l15  = lane & 15;
    const int lhi  = lane >> 4;
    const int c0   = blockIdx.x;            // one class per block

    // W staging: thread covers row jrow (0..63), k-quarter jq (16 floats)
    const int jrow = tid >> 2;
    const int jq   = tid & 3;
    const float* wbase = w + (size_t)c0 * (RDIM * NDIM) + (size_t)jrow * NDIM + jq * 16;
    const float* bbase = bias + (size_t)c0 * NDIM + jq * 16;

    f32x4 acc[4][4];
    #pragma unroll
    for (int m = 0; m < 4; ++m)
        #pragma unroll
        for (int n = 0; n < 4; ++n)
            acc[m][n] = (f32x4){0.f, 0.f, 0.f, 0.f};

    float sbp = 0.f;
    const int swr = (l15 & 7) << 4;
    const int sww = (jrow & 7) << 4;

    for (int t = 0; t < NT; ++t) {
        // ---- stage W tile (HBM stream) + bias (L2) into regs
        const float4* wsrc = reinterpret_cast<const float4*>(wbase + t * BK);
        const float4* bsrc = reinterpret_cast<const float4*>(bbase + t * BK);
        float4 w0 = wsrc[0], w1 = wsrc[1], w2 = wsrc[2], w3 = wsrc[3];
        float4 b0 = bsrc[0], b1 = bsrc[1], b2 = bsrc[2], b3 = bsrc[3];

        // ---- async-stage x tile t (fire-and-forget; drained by barrier #1)
        #pragma unroll
        for (int q = 0; q < 8; ++q)
            gload16(xws + (size_t)t * 32768 + wv * 8192 + q * 1024 + lane * 16,
                    lds_x + wv * 8192 + q * 1024);

        // ---- convert W -> bf16 swizzled LDS, fused fp32 Sb partial
        sbp += w0.x*b0.x + w0.y*b0.y + w0.z*b0.z + w0.w*b0.w
             + w1.x*b1.x + w1.y*b1.y + w1.z*b1.z + w1.w*b1.w
             + w2.x*b2.x + w2.y*b2.y + w2.z*b2.z + w2.w*b2.w
             + w3.x*b3.x + w3.y*b3.y + w3.z*b3.z + w3.w*b3.w;
        {
            char* rowp = lds_w + jrow * 128;
            uint4 pa = {pk2(w0.x, w0.y), pk2(w0.z, w0.w), pk2(w1.x, w1.y), pk2(w1.z, w1.w)};
            uint4 pb = {pk2(w2.x, w2.y), pk2(w2.z, w2.w), pk2(w3.x, w3.y), pk2(w3.z, w3.w)};
            *reinterpret_cast<uint4*>(rowp + ((jq * 32) ^ sww))      = pa;
            *reinterpret_cast<uint4*>(rowp + ((jq * 32 + 16) ^ sww)) = pb;
        }

        __syncthreads();   // barrier #1: x gloads + W ds_writes all visible

        // ---- MFMA: 2 k-steps of 32
        #pragma unroll
        for (int ks = 0; ks < 2; ++ks) {
            bf16x8 af[4];
            bf16x8 bfr[4];
            #pragma unroll
            for (int m = 0; m < 4; ++m) {
                const int row = wv * 64 + m * 16 + l15;
                af[m] = *reinterpret_cast<const bf16x8*>(
                    lds_x + row * 128 + ((ks * 64 + lhi * 16) ^ swr));
            }
            #pragma unroll
            for (int n = 0; n < 4; ++n) {
                const int row = n * 16 + l15;
                bfr[n] = *reinterpret_cast<const bf16x8*>(
                    lds_w + row * 128 + ((ks * 64 + lhi * 16) ^ swr));
            }
            #pragma unroll
            for (int m = 0; m < 4; ++m)
                #pragma unroll
                for (int n = 0; n < 4; ++n)
                    acc[m][n] = __builtin_amdgcn_mfma_f32_16x16x32_bf16(
                        af[m], bfr[n], acc[m][n], 0, 0, 0);
        }

        __syncthreads();   // barrier #2: all reads done before next overwrite
    }

    // ---- Sb: reduce 4 k-quarters (consecutive lanes), publish
    sbp += __shfl_xor(sbp, 1);
    sbp += __shfl_xor(sbp, 2);
    if (jq == 0) sb_lds[jrow] = sbp;
    __syncthreads();

    float sb[4];
    #pragma unroll
    for (int n = 0; n < 4; ++n) sb[n] = sb_lds[n * 16 + l15];

    // ---- epilogue: out[b,c0] = sum_r (S - Sb)^2 ; butterfly over 16 lanes
    #pragma unroll
    for (int m = 0; m < 4; ++m) {
        #pragma unroll
        for (int rg = 0; rg < 4; ++rg) {
            float p = 0.f;
            #pragma unroll
            for (int n = 0; n < 4; ++n) {
                const float d = acc[m][n][rg] - sb[n];
                p += d * d;
            }
            #pragma unroll
            for (int s = 1; s < 16; s <<= 1)
                p += __shfl_xor(p, s);
            if (l15 == 0) {
                const int b = wv * 64 + m * 16 + lhi * 4 + rg;
                out[(size_t)b * CDIM + c0] = p;
            }
        }
    }
}

// ---------------------------------------------------------------------------
// Fallback (round-1 proven kernel) for ws_size < 256 KB
// ---------------------------------------------------------------------------
__global__ __launch_bounds__(256, 2)
void Mahalanobis_fallback_kernel(const float* __restrict__ x,
                                 const float* __restrict__ w,
                                 const float* __restrict__ bias,
                                 float* __restrict__ out)
{
    __shared__ alignas(16) char lds_x[BDIM * BK * 2];
    __shared__ alignas(16) char lds_w[128 * BK * 2];
    __shared__ alignas(16) float bias_lds[2 * NDIM];
    __shared__ float sb_lds[128];

    const int tid  = threadIdx.x;
    const int lane = tid & 63;
    const int wv   = tid >> 6;
    const int l15  = lane & 15;
    const int lhi  = lane >> 4;
    const int c0   = blockIdx.x * 2;

    reinterpret_cast<float4*>(bias_lds)[tid] =
        reinterpret_cast<const float4*>(bias + (size_t)c0 * NDIM)[tid];

    f32x4 acc[4][8];
    #pragma unroll
    for (int m = 0; m < 4; ++m)
        #pragma unroll
        for (int n = 0; n < 8; ++n)
            acc[m][n] = (f32x4){0.f, 0.f, 0.f, 0.f};

    const int jrow = tid >> 1;
    const int jh   = tid & 1;
    const int cl   = jrow >> 6;
    const float* wbase  = w + (size_t)(c0 + cl) * (RDIM * NDIM)
                            + (size_t)(jrow & 63) * NDIM + jh * 32;
    const float* blbase = bias_lds + cl * NDIM + jh * 32;
    const int xrow = tid >> 2;
    const int xq   = tid & 3;

    float sbp = 0.f;
    __syncthreads();

    for (int kk = 0; kk < NDIM; kk += BK) {
        #pragma unroll
        for (int p = 0; p < 4; ++p) {
            const int r = p * 64 + xrow;
            const float4* src = reinterpret_cast<const float4*>(
                x + (size_t)r * NDIM + kk + xq * 16);
            float4 v0 = src[0], v1 = src[1], v2 = src[2], v3 = src[3];
            uint4 pa = {pk2(v0.x, v0.y), pk2(v0.z, v0.w), pk2(v1.x, v1.y), pk2(v1.z, v1.w)};
            uint4 pb = {pk2(v2.x, v2.y), pk2(v2.z, v2.w), pk2(v3.x, v3.y), pk2(v3.z, v3.w)};
            const int sw = (r & 7) << 4;
            char* rowp = lds_x + r * (BK * 2);
            *reinterpret_cast<uint4*>(rowp + ((xq * 32) ^ sw))      = pa;
            *reinterpret_cast<uint4*>(rowp + ((xq * 32 + 16) ^ sw)) = pb;
        }
        {
            const float4* src = reinterpret_cast<const float4*>(wbase + kk);
            const float4* bl  = reinterpret_cast<const float4*>(blbase + kk);
            char* rowp = lds_w + jrow * (BK * 2);
            const int sw = (jrow & 7) << 4;
            #pragma unroll
            for (int i2 = 0; i2 < 4; ++i2) {
                float4 va = src[i2 * 2];
                float4 vb = src[i2 * 2 + 1];
                float4 ba = bl[i2 * 2];
                float4 bb = bl[i2 * 2 + 1];
                sbp += va.x * ba.x + va.y * ba.y + va.z * ba.z + va.w * ba.w
                     + vb.x * bb.x + vb.y * bb.y + vb.z * bb.z + vb.w * bb.w;
                uint4 pkv = {pk2(va.x, va.y), pk2(va.z, va.w),
                             pk2(vb.x, vb.y), pk2(vb.z, vb.w)};
                *reinterpret_cast<uint4*>(rowp + ((jh * 64 + i2 * 16) ^ sw)) = pkv;
            }
        }
        __syncthreads();
        #pragma unroll
        for (int ks = 0; ks < 2; ++ks) {
            bf16x8 af[4];
            bf16x8 bfr[8];
            const int swr = (l15 & 7) << 4;
            #pragma unroll
            for (int m = 0; m < 4; ++m) {
                const int row = wv * 64 + m * 16 + l15;
                af[m] = *reinterpret_cast<const bf16x8*>(
                    lds_x + row * (BK * 2) + ((ks * 64 + lhi * 16) ^ swr));
            }
            #pragma unroll
            for (int n = 0; n < 8; ++n) {
                const int row = n * 16 + l15;
                bfr[n] = *reinterpret_cast<const bf16x8*>(
                    lds_w + row * (BK * 2) + ((ks * 64 + lhi * 16) ^ swr));
            }
            #pragma unroll
            for (int m = 0; m < 4; ++m)
                #pragma unroll
                for (int n = 0; n < 8; ++n)
                    acc[m][n] = __builtin_amdgcn_mfma_f32_16x16x32_bf16(
                        af[m], bfr[n], acc[m][n], 0, 0, 0);
        }
        __syncthreads();
    }

    sbp += __shfl_xor(sbp, 1);
    if (jh == 0) sb_lds[jrow] = sbp;
    __syncthreads();

    float sb[8];
    #pragma unroll
    for (int n = 0; n < 8; ++n) sb[n] = sb_lds[n * 16 + l15];

    #pragma unroll
    for (int m = 0; m < 4; ++m) {
        #pragma unroll
        for (int rg = 0; rg < 4; ++rg) {
            float p0 = 0.f, p1 = 0.f;
            #pragma unroll
            for (int n = 0; n < 4; ++n) {
                const float d0 = acc[m][n][rg]     - sb[n];
                const float d1 = acc[m][n + 4][rg] - sb[n + 4];
                p0 += d0 * d0;
                p1 += d1 * d1;
            }
            #pragma unroll
            for (int s = 1; s < 16; s <<= 1) {
                p0 += __shfl_xor(p0, s);
                p1 += __shfl_xor(p1, s);
            }
            if (l15 == 0) {
                const int b = wv * 64 + m * 16 + lhi * 4 + rg;
                float2 o2 = {p0, p1};
                *reinterpret_cast<float2*>(out + (size_t)b * CDIM + c0) = o2;
            }
        }
    }
}

extern "C" void kernel_launch(void* const* d_in, const int* in_sizes, int n_in,
                              void* d_out, int out_size, void* d_ws, size_t ws_size,
                              hipStream_t stream) {
    const float* x    = (const float*)d_in[0];
    const float* w    = (const float*)d_in[1];
    const float* bias = (const float*)d_in[2];
    float* out = (float*)d_out;

    if (ws_size >= (size_t)(BDIM * NDIM * 2)) {
        hipLaunchKernelGGL(Mahalanobis_xconv_kernel, dim3(64), dim3(256), 0, stream,
                           x, (uint4*)d_ws);
        hipLaunchKernelGGL(Mahalanobis_72834055405642_kernel, dim3(CDIM), dim3(256),
                           0, stream, (const char*)d_ws, w, bias, out);
    } else {
        hipLaunchKernelGGL(Mahalanobis_fallback_kernel, dim3(CDIM / 2), dim3(256),
                           0, stream, x, w, bias, out);
    }
}